// Round 1
// baseline (1700.182 us; speedup 1.0000x reference)
//
#include <hip/hip_runtime.h>
#include <math.h>

#define NN 64
#define CC 96
#define HH 18
#define WW 32
#define HWP 576
#define SIN 320
#define NHEADS 4
#define HDIM 24
#define HIDC 96
#define ENCC 320

// ws layout (floats). Aliasing: qkv dead after attn -> y/z/rh reuse its space;
// o dead after proj -> h_new reuses its space. Peak = 14,331,904 floats = 57.3 MB.
#define MOD_OFF   0
#define A_OFF     12288
#define Y_OFF     (A_OFF)
#define Z_OFF     (A_OFF + 3538944)
#define RH_OFF    (A_OFF + 7077888)
#define O_OFF     (A_OFF + 10616832)
#define HN_OFF    (O_OFF)
#define PART_OFF  (O_OFF + 3538944)

// ---------------- modulation: mod = x_state @ W_mod + b_mod ----------------
__global__ __launch_bounds__(192) void k_mod(const float* __restrict__ xs,
    const float* __restrict__ Wm, const float* __restrict__ bm,
    float* __restrict__ mod) {
  __shared__ float s[SIN];
  int n = blockIdx.x;
  for (int i = threadIdx.x; i < SIN; i += 192) s[i] = xs[n * SIN + i];
  __syncthreads();
  int j = threadIdx.x;  // 0..191
  float acc = bm[j];
  #pragma unroll 4
  for (int k = 0; k < SIN; ++k) acc = fmaf(s[k], Wm[k * 192 + j], acc);
  mod[n * 192 + j] = acc;
}

// ---------------- FiLM + qkv GEMM: qkv[n,p,j] ----------------
__global__ __launch_bounds__(288) void k_qkv(const float* __restrict__ x,
    const float* __restrict__ mod, const float* __restrict__ Wq,
    const float* __restrict__ bq, float* __restrict__ qkv) {
  int n = blockIdx.y, p0 = blockIdx.x * 4;
  __shared__ float xm[CC][4];
  for (int idx = threadIdx.x; idx < CC * 4; idx += 288) {
    int c = idx >> 2, pi = idx & 3;
    xm[c][pi] = x[((size_t)n * CC + c) * HWP + p0 + pi] * mod[n * 192 + c]
                + mod[n * 192 + CC + c];
  }
  __syncthreads();
  int j = threadIdx.x;  // 0..287
  float a0 = bq[j], a1 = a0, a2 = a0, a3 = a0;
  #pragma unroll 4
  for (int c = 0; c < CC; ++c) {
    float w = Wq[c * 288 + j];
    a0 = fmaf(xm[c][0], w, a0);
    a1 = fmaf(xm[c][1], w, a1);
    a2 = fmaf(xm[c][2], w, a2);
    a3 = fmaf(xm[c][3], w, a3);
  }
  float* out = qkv + ((size_t)n * HWP + p0) * 288 + j;
  out[0] = a0; out[288] = a1; out[576] = a2; out[864] = a3;
}

// ---------------- attention: one block per (n, head) ----------------
__global__ __launch_bounds__(576) void k_attn(const float* __restrict__ qkv,
                                              float* __restrict__ o) {
  int head = blockIdx.x, n = blockIdx.y;
  __shared__ float ks[HWP][HDIM];
  __shared__ float vs[HWP][HDIM];
  const float* base = qkv + (size_t)n * HWP * 288;
  int koff = CC + head * HDIM, voff = 2 * CC + head * HDIM;
  for (int idx = threadIdx.x; idx < HWP * HDIM; idx += 576) {
    int p = idx / HDIM, d = idx % HDIM;
    ks[p][d] = base[p * 288 + koff + d];
    vs[p][d] = base[p * 288 + voff + d];
  }
  __syncthreads();
  int p = threadIdx.x;  // query index
  float q[HDIM];
  const float scale = 0.2041241452319315f;  // 1/sqrt(24)
  #pragma unroll
  for (int d = 0; d < HDIM; ++d) q[d] = base[p * 288 + head * HDIM + d] * scale;
  float m = -1e30f, l = 0.f, acc[HDIM];
  #pragma unroll
  for (int d = 0; d < HDIM; ++d) acc[d] = 0.f;
  for (int j = 0; j < HWP; ++j) {
    float s = 0.f;
    #pragma unroll
    for (int d = 0; d < HDIM; ++d) s = fmaf(q[d], ks[j][d], s);
    if (s > m) {
      float corr = __expf(m - s);
      l *= corr;
      #pragma unroll
      for (int d = 0; d < HDIM; ++d) acc[d] *= corr;
      m = s;
    }
    float e = __expf(s - m);
    l += e;
    #pragma unroll
    for (int d = 0; d < HDIM; ++d) acc[d] = fmaf(e, vs[j][d], acc[d]);
  }
  float inv = 1.f / l;
  float* op = o + ((size_t)n * HWP + p) * CC + head * HDIM;
  #pragma unroll
  for (int d = 0; d < HDIM; ++d) op[d] = acc[d] * inv;
}

// ---------------- proj + residual -> y (NCHW) ----------------
__global__ __launch_bounds__(192) void k_proj(const float* __restrict__ o,
    const float* __restrict__ Wp, const float* __restrict__ bp,
    const float* __restrict__ x, float* __restrict__ y) {
  int n = blockIdx.y, p0 = blockIdx.x * 8;
  __shared__ float os[8][CC];
  for (int idx = threadIdx.x; idx < 8 * CC; idx += 192)
    os[idx / CC][idx % CC] = o[((size_t)n * HWP + p0 + idx / CC) * CC + idx % CC];
  __syncthreads();
  #pragma unroll
  for (int k = 0; k < 4; ++k) {
    int idx = threadIdx.x + k * 192;
    int pi = idx / CC, j = idx % CC;
    float acc = bp[j];
    #pragma unroll 4
    for (int c = 0; c < CC; ++c) acc = fmaf(os[pi][c], Wp[c * CC + j], acc);
    int gp = p0 + pi;
    size_t yi = ((size_t)n * CC + j) * HWP + gp;
    y[yi] = x[yi] + acc;
  }
}

// ---------------- conv zr (192->192) + sigmoid -> z, r*h ----------------
__global__ __launch_bounds__(576) void k_conv_zr(const float* __restrict__ y,
    const float* __restrict__ hidden, const int* __restrict__ keys,
    const float* __restrict__ Kw, const float* __restrict__ bb,
    float* __restrict__ z, float* __restrict__ rh) {
  int n = blockIdx.y, oc0 = blockIdx.x * 8;
  int key = keys[n];
  __shared__ float plane[HWP];
  int p = threadIdx.x;
  int py = p >> 5, px = p & 31;
  float acc[8];
  #pragma unroll
  for (int l = 0; l < 8; ++l) acc[l] = bb[oc0 + l];
  for (int ic = 0; ic < 2 * CC; ++ic) {
    __syncthreads();
    const float* src = (ic < CC) ? (y + ((size_t)n * CC + ic) * HWP)
                                 : (hidden + ((size_t)key * HIDC + (ic - CC)) * HWP);
    plane[p] = src[p];
    __syncthreads();
    float tap[9];
    #pragma unroll
    for (int dy = 0; dy < 3; ++dy) {
      int yy = py + dy - 1;
      #pragma unroll
      for (int dx = 0; dx < 3; ++dx) {
        int xx = px + dx - 1;
        tap[dy * 3 + dx] = (yy >= 0 && yy < HH && xx >= 0 && xx < WW)
                               ? plane[yy * WW + xx] : 0.f;
      }
    }
    const float* wp = Kw + ((size_t)oc0 * (2 * CC) + ic) * 9;
    #pragma unroll
    for (int l = 0; l < 8; ++l) {
      #pragma unroll
      for (int t = 0; t < 9; ++t)
        acc[l] = fmaf(tap[t], wp[l * (2 * CC) * 9 + t], acc[l]);
    }
  }
  if (oc0 < CC) {
    #pragma unroll
    for (int l = 0; l < 8; ++l) {
      float s = 1.f / (1.f + __expf(-acc[l]));
      z[((size_t)n * CC + oc0 + l) * HWP + p] = s;
    }
  } else {
    #pragma unroll
    for (int l = 0; l < 8; ++l) {
      int c2 = oc0 + l - CC;
      float s = 1.f / (1.f + __expf(-acc[l]));
      rh[((size_t)n * CC + c2) * HWP + p] =
          s * hidden[((size_t)key * HIDC + c2) * HWP + p];
    }
  }
}

// ---------------- conv c (192->96) + tanh + GRU blend -> h_new ----------------
__global__ __launch_bounds__(576) void k_conv_c(const float* __restrict__ y,
    const float* __restrict__ rh, const int* __restrict__ keys,
    const float* __restrict__ z, const float* __restrict__ hidden,
    const float* __restrict__ Kw, const float* __restrict__ bb,
    float* __restrict__ hn) {
  int n = blockIdx.y, oc0 = blockIdx.x * 8;
  int key = keys[n];
  __shared__ float plane[HWP];
  int p = threadIdx.x;
  int py = p >> 5, px = p & 31;
  float acc[8];
  #pragma unroll
  for (int l = 0; l < 8; ++l) acc[l] = bb[oc0 + l];
  for (int ic = 0; ic < 2 * CC; ++ic) {
    __syncthreads();
    const float* src = (ic < CC) ? (y + ((size_t)n * CC + ic) * HWP)
                                 : (rh + ((size_t)n * CC + (ic - CC)) * HWP);
    plane[p] = src[p];
    __syncthreads();
    float tap[9];
    #pragma unroll
    for (int dy = 0; dy < 3; ++dy) {
      int yy = py + dy - 1;
      #pragma unroll
      for (int dx = 0; dx < 3; ++dx) {
        int xx = px + dx - 1;
        tap[dy * 3 + dx] = (yy >= 0 && yy < HH && xx >= 0 && xx < WW)
                               ? plane[yy * WW + xx] : 0.f;
      }
    }
    const float* wp = Kw + ((size_t)oc0 * (2 * CC) + ic) * 9;
    #pragma unroll
    for (int l = 0; l < 8; ++l) {
      #pragma unroll
      for (int t = 0; t < 9; ++t)
        acc[l] = fmaf(tap[t], wp[l * (2 * CC) * 9 + t], acc[l]);
    }
  }
  #pragma unroll
  for (int l = 0; l < 8; ++l) {
    int oc = oc0 + l;
    float cval = tanhf(acc[l]);
    float zv = z[((size_t)n * CC + oc) * HWP + p];
    float hv = hidden[((size_t)key * HIDC + oc) * HWP + p];
    hn[((size_t)n * CC + oc) * HWP + p] = (1.f - zv) * hv + zv * cval;
  }
}

// ---------------- 2x2 mean pool -> out[0 : 884736] ----------------
__global__ void k_pool(const float* __restrict__ hn, float* __restrict__ out) {
  int idx = blockIdx.x * 256 + threadIdx.x;
  if (idx >= NN * CC * 9 * 16) return;
  int j = idx & 15, i = (idx >> 4) % 9, nc = idx / 144;
  const float* b = hn + (size_t)nc * HWP + (2 * i) * WW + 2 * j;
  out[idx] = 0.25f * (b[0] + b[1] + b[WW] + b[WW + 1]);
}

// ---------------- PosConv partial: per (n, p-chunk) max of W_pos@(h+pos) ----------------
__global__ __launch_bounds__(320) void k_enc(const float* __restrict__ hn,
    const float* __restrict__ pos, const float* __restrict__ Wp,
    const float* __restrict__ bp, float* __restrict__ part) {
  int n = blockIdx.y, pb = blockIdx.x;
  __shared__ float e[CC];
  int o = threadIdx.x;  // 0..319
  float w[CC];
  #pragma unroll
  for (int c = 0; c < CC; c += 4) {
    float4 v = *reinterpret_cast<const float4*>(Wp + (size_t)o * CC + c);
    w[c] = v.x; w[c + 1] = v.y; w[c + 2] = v.z; w[c + 3] = v.w;
  }
  float mx = -1e30f;
  int pend = pb * 72 + 72;
  for (int p = pb * 72; p < pend; ++p) {
    __syncthreads();
    if (o < CC) e[o] = hn[((size_t)n * CC + o) * HWP + p] + pos[o * HWP + p];
    __syncthreads();
    float acc = 0.f;
    #pragma unroll
    for (int c = 0; c < CC; ++c) acc = fmaf(e[c], w[c], acc);
    mx = fmaxf(mx, acc);
  }
  part[((size_t)n * 8 + pb) * ENCC + o] = mx + bp[o];
}

__global__ __launch_bounds__(320) void k_reduce(const float* __restrict__ part,
                                                float* __restrict__ out) {
  int n = blockIdx.x, o = threadIdx.x;
  float mx = part[((size_t)n * 8) * ENCC + o];
  #pragma unroll
  for (int pb = 1; pb < 8; ++pb)
    mx = fmaxf(mx, part[((size_t)n * 8 + pb) * ENCC + o]);
  out[NN * CC * 144 + n * ENCC + o] = mx;
}

extern "C" void kernel_launch(void* const* d_in, const int* in_sizes, int n_in,
                              void* d_out, int out_size, void* d_ws, size_t ws_size,
                              hipStream_t stream) {
  const float* x       = (const float*)d_in[0];
  const float* x_state = (const float*)d_in[1];
  const int*   keys    = (const int*)d_in[2];
  const float* hidden  = (const float*)d_in[3];
  const float* W_mod   = (const float*)d_in[4];
  const float* b_mod   = (const float*)d_in[5];
  const float* W_qkv   = (const float*)d_in[6];
  const float* b_qkv   = (const float*)d_in[7];
  const float* W_proj  = (const float*)d_in[8];
  const float* b_proj  = (const float*)d_in[9];
  const float* K_zr    = (const float*)d_in[10];
  const float* b_zr    = (const float*)d_in[11];
  const float* K_c     = (const float*)d_in[12];
  const float* b_c     = (const float*)d_in[13];
  const float* pos_emb = (const float*)d_in[14];
  const float* W_pos   = (const float*)d_in[15];
  const float* b_pos   = (const float*)d_in[16];
  float* out = (float*)d_out;
  float* ws  = (float*)d_ws;

  k_mod<<<NN, 192, 0, stream>>>(x_state, W_mod, b_mod, ws + MOD_OFF);
  k_qkv<<<dim3(144, NN), 288, 0, stream>>>(x, ws + MOD_OFF, W_qkv, b_qkv,
                                           ws + A_OFF);
  k_attn<<<dim3(NHEADS, NN), 576, 0, stream>>>(ws + A_OFF, ws + O_OFF);
  k_proj<<<dim3(72, NN), 192, 0, stream>>>(ws + O_OFF, W_proj, b_proj, x,
                                           ws + Y_OFF);
  k_conv_zr<<<dim3(24, NN), 576, 0, stream>>>(ws + Y_OFF, hidden, keys, K_zr,
                                              b_zr, ws + Z_OFF, ws + RH_OFF);
  k_conv_c<<<dim3(12, NN), 576, 0, stream>>>(ws + Y_OFF, ws + RH_OFF, keys,
                                             ws + Z_OFF, hidden, K_c, b_c,
                                             ws + HN_OFF);
  k_pool<<<3456, 256, 0, stream>>>(ws + HN_OFF, out);
  k_enc<<<dim3(8, NN), 320, 0, stream>>>(ws + HN_OFF, pos_emb, W_pos, b_pos,
                                         ws + PART_OFF);
  k_reduce<<<NN, 320, 0, stream>>>(ws + PART_OFF, out);
}